// Round 1
// baseline (162.308 us; speedup 1.0000x reference)
//
#include <hip/hip_runtime.h>
#include <hip/hip_bf16.h>

#define NUM_AGES 100
#define FEAT 512
#define BATCH 4096
#define EPSF 1e-6f
#define INV_T 10.0f

#define BM 128
#define BN 128
#define BK 32
#define GRID_N (BATCH / BN)
#define GRID_M (BATCH / BM)

typedef __bf16 bf16_t;
typedef __bf16 v8bf __attribute__((ext_vector_type(8)));
typedef float v4f __attribute__((ext_vector_type(4)));

// async global->LDS, 16B per lane; LDS dest is wave-uniform base + lane*16
__device__ __forceinline__ void async16(const void* g, void* l) {
  __builtin_amdgcn_global_load_lds(
      (const __attribute__((address_space(1))) void*)g,
      (__attribute__((address_space(3))) void*)l, 16, 0, 0);
}

// ---------------- kernel 1: per-sample prep ----------------
// vf = (c_next-c_cur)/(|.|+eps), vb = (c_prev-c_cur)/(|.|+eps), w = vb - vf
// outputs: zb (bf16), wb (bf16), sq = |z|^2 (f32), hd = z.w (f32)
__global__ __launch_bounds__(256) void prep_kernel(
    const float* __restrict__ z, const int* __restrict__ ages,
    const float* __restrict__ proxies,
    bf16_t* __restrict__ zb, bf16_t* __restrict__ wb,
    float* __restrict__ sq, float* __restrict__ hd)
{
  int j = blockIdx.x;
  int t = threadIdx.x;
  int a = ages[j];
  if (a < 0) a = 0;
  if (a > NUM_AGES - 1) a = NUM_AGES - 1;
  const float* cc = proxies + (size_t)a * FEAT;
  const float* cn = proxies + (size_t)(a + 1 > NUM_AGES - 1 ? NUM_AGES - 1 : a + 1) * FEAT;
  const float* cp = proxies + (size_t)(a - 1 < 0 ? 0 : a - 1) * FEAT;
  const float* zr = z + (size_t)j * FEAT;

  float zf[2], dff[2], dbf[2];
  float s_ff = 0.f, s_bb = 0.f, s_zz = 0.f, s_zf = 0.f, s_zb = 0.f;
#pragma unroll
  for (int e = 0; e < 2; ++e) {
    int c = t + e * 256;
    float ccv = cc[c];
    dff[e] = cn[c] - ccv;
    dbf[e] = cp[c] - ccv;
    zf[e] = zr[c];
    s_ff += dff[e] * dff[e];
    s_bb += dbf[e] * dbf[e];
    s_zz += zf[e] * zf[e];
    s_zf += zf[e] * dff[e];
    s_zb += zf[e] * dbf[e];
  }
#pragma unroll
  for (int off = 32; off > 0; off >>= 1) {
    s_ff += __shfl_down(s_ff, off, 64);
    s_bb += __shfl_down(s_bb, off, 64);
    s_zz += __shfl_down(s_zz, off, 64);
    s_zf += __shfl_down(s_zf, off, 64);
    s_zb += __shfl_down(s_zb, off, 64);
  }
  __shared__ float red[4][5];
  int wv = t >> 6, lane = t & 63;
  if (lane == 0) {
    red[wv][0] = s_ff; red[wv][1] = s_bb; red[wv][2] = s_zz;
    red[wv][3] = s_zf; red[wv][4] = s_zb;
  }
  __syncthreads();
  float ff = red[0][0] + red[1][0] + red[2][0] + red[3][0];
  float bb = red[0][1] + red[1][1] + red[2][1] + red[3][1];
  float zz = red[0][2] + red[1][2] + red[2][2] + red[3][2];
  float zdf = red[0][3] + red[1][3] + red[2][3] + red[3][3];
  float zdb = red[0][4] + red[1][4] + red[2][4] + red[3][4];

  float rf = 1.0f / (sqrtf(ff) + EPSF);
  float rb = 1.0f / (sqrtf(bb) + EPSF);
#pragma unroll
  for (int e = 0; e < 2; ++e) {
    int c = t + e * 256;
    float wval = dbf[e] * rb - dff[e] * rf;
    wb[(size_t)j * FEAT + c] = (bf16_t)wval;
    zb[(size_t)j * FEAT + c] = (bf16_t)zf[e];
  }
  if (t == 0) {
    sq[j] = zz;
    hd[j] = rb * zdb - rf * zdf;
  }
}

// ---------------- kernel 2: fused pairwise tile ----------------
__global__ __launch_bounds__(256) void pair_kernel(
    const bf16_t* __restrict__ zb, const bf16_t* __restrict__ wb,
    const float* __restrict__ sq, const float* __restrict__ hd,
    const int* __restrict__ ages, float* __restrict__ partial)
{
  __shared__ __attribute__((aligned(16))) char lds[3 * BM * BK * 2]; // A | Z | W
  __shared__ float s_sqi[BM];
  __shared__ int   s_agei[BM];
  __shared__ float s_sqj[BN];
  __shared__ float s_hdj[BN];
  __shared__ int   s_agej[BN];
  __shared__ float wsum[4];

  int t = threadIdx.x;
  int wv = t >> 6, lane = t & 63;
  int i0 = blockIdx.y * BM, j0 = blockIdx.x * BN;

  if (t < BM) {
    s_sqi[t] = sq[i0 + t];
    s_agei[t] = ages[i0 + t];
  } else {
    int u = t - BM;
    s_sqj[u] = sq[j0 + u];
    s_hdj[u] = hd[j0 + u];
    s_agej[u] = ages[j0 + u];
  }

  v4f accG[4][4], accH[4][4];
#pragma unroll
  for (int a = 0; a < 4; ++a)
#pragma unroll
    for (int b = 0; b < 4; ++b) {
      accG[a][b] = (v4f){0.f, 0.f, 0.f, 0.f};
      accH[a][b] = (v4f){0.f, 0.f, 0.f, 0.f};
    }

  int wm = wv >> 1, wn = wv & 1;
  int lm = lane & 15, q = lane >> 4;

  const bf16_t* gA = zb + (size_t)i0 * FEAT;
  const bf16_t* gZ = zb + (size_t)j0 * FEAT;
  const bf16_t* gW = wb + (size_t)j0 * FEAT;

  int grow = lane >> 2;        // row within 16-row chunk
  int gcol = (lane & 3) * 8;   // bf16 element offset within 32-wide K slab

  for (int k0 = 0; k0 < FEAT; k0 += BK) {
#pragma unroll
    for (int c2 = 0; c2 < 2; ++c2) {
      int chunk = wv * 2 + c2;                         // 0..7 : 16 rows each
      int row = chunk * 16 + grow;
      size_t goff = (size_t)row * FEAT + (size_t)(k0 + gcol);
      char* ldst = lds + chunk * 1024;                 // wave-uniform base
      async16(gA + goff, ldst);
      async16(gZ + goff, ldst + 8192);
      async16(gW + goff, ldst + 16384);
    }
    __syncthreads();

    v8bf afr[4], bz[4], bw[4];
#pragma unroll
    for (int mi = 0; mi < 4; ++mi) {
      int r = wm * 64 + mi * 16 + lm;
      afr[mi] = *(const v8bf*)(lds + r * 64 + q * 16);
    }
#pragma unroll
    for (int ni = 0; ni < 4; ++ni) {
      int r = wn * 64 + ni * 16 + lm;
      bz[ni] = *(const v8bf*)(lds + 8192 + r * 64 + q * 16);
      bw[ni] = *(const v8bf*)(lds + 16384 + r * 64 + q * 16);
    }
#pragma unroll
    for (int mi = 0; mi < 4; ++mi)
#pragma unroll
      for (int ni = 0; ni < 4; ++ni) {
        accG[mi][ni] = __builtin_amdgcn_mfma_f32_16x16x32_bf16(afr[mi], bz[ni], accG[mi][ni], 0, 0, 0);
        accH[mi][ni] = __builtin_amdgcn_mfma_f32_16x16x32_bf16(afr[mi], bw[ni], accH[mi][ni], 0, 0, 0);
      }
    __syncthreads();
  }

  // epilogue: C/D layout col = lane&15 (-> j), row = q*4 + reg (-> i)
  float sqi_l[16];
  int agei_l[16];
#pragma unroll
  for (int mi = 0; mi < 4; ++mi)
#pragma unroll
    for (int r = 0; r < 4; ++r) {
      int il = wm * 64 + mi * 16 + q * 4 + r;
      sqi_l[mi * 4 + r] = s_sqi[il];
      agei_l[mi * 4 + r] = s_agei[il];
    }

  float tsum = 0.f;
#pragma unroll
  for (int ni = 0; ni < 4; ++ni) {
    int jl = wn * 64 + ni * 16 + lm;
    float sqj = s_sqj[jl];
    float hdj = s_hdj[jl];
    int aj = s_agej[jl];
#pragma unroll
    for (int mi = 0; mi < 4; ++mi) {
#pragma unroll
      for (int r = 0; r < 4; ++r) {
        float g = accG[mi][ni][r];
        float h = accH[mi][ni][r];
        float sqi = sqi_l[mi * 4 + r];
        int ai = agei_l[mi * 4 + r];
        float d2 = fmaxf(sqi + sqj - 2.0f * g, 0.0f);
        float denom = sqrtf(d2) + EPSF;
        float arg = (h - hdj) * INV_T / denom;
        float x = fabsf(arg);
        float sp = fmaxf(arg, 0.0f) + __logf(1.0f + __expf(-x));
        tsum += (ai < aj) ? sp : 0.0f;
      }
    }
  }

#pragma unroll
  for (int off = 32; off > 0; off >>= 1) tsum += __shfl_down(tsum, off, 64);
  if (lane == 0) wsum[wv] = tsum;
  __syncthreads();
  if (t == 0)
    partial[blockIdx.y * gridDim.x + blockIdx.x] = wsum[0] + wsum[1] + wsum[2] + wsum[3];
}

// ---------------- kernel 3: final reduce ----------------
__global__ __launch_bounds__(256) void reduce_kernel(
    const float* __restrict__ partial, int n, float* __restrict__ out)
{
  int t = threadIdx.x;
  double s = 0.0;
  for (int idx = t; idx < n; idx += 256) s += (double)partial[idx];
#pragma unroll
  for (int off = 32; off > 0; off >>= 1) s += __shfl_down(s, off, 64);
  __shared__ double ws[4];
  int wv = t >> 6, lane = t & 63;
  if (lane == 0) ws[wv] = s;
  __syncthreads();
  if (t == 0) {
    double tot = ws[0] + ws[1] + ws[2] + ws[3];
    out[0] = (float)(tot / ((double)BATCH * (double)(BATCH - 1)));
  }
}

extern "C" void kernel_launch(void* const* d_in, const int* in_sizes, int n_in,
                              void* d_out, int out_size, void* d_ws, size_t ws_size,
                              hipStream_t stream) {
  const float* z = (const float*)d_in[0];
  const int* ages = (const int*)d_in[1];
  const float* proxies = (const float*)d_in[2];
  float* out = (float*)d_out;

  char* ws = (char*)d_ws;
  bf16_t* zb = (bf16_t*)ws;                                  // 4 MB
  bf16_t* wb = (bf16_t*)(ws + (size_t)4 * 1024 * 1024);      // 4 MB
  float* sq = (float*)(ws + (size_t)8 * 1024 * 1024);        // 16 KB
  float* hd = (float*)(ws + (size_t)8 * 1024 * 1024 + 16384);
  float* partial = (float*)(ws + (size_t)8 * 1024 * 1024 + 32768);

  prep_kernel<<<BATCH, 256, 0, stream>>>(z, ages, proxies, zb, wb, sq, hd);
  dim3 grid(GRID_N, GRID_M);
  pair_kernel<<<grid, 256, 0, stream>>>(zb, wb, sq, hd, ages, partial);
  reduce_kernel<<<1, 256, 0, stream>>>(partial, GRID_N * GRID_M, out);
}

// Round 2
// 159.472 us; speedup vs baseline: 1.0178x; 1.0178x over previous
//
#include <hip/hip_runtime.h>
#include <hip/hip_bf16.h>

#define NUM_AGES 100
#define FEAT 512
#define BATCH 4096
#define EPSF 1e-6f
#define INV_T 10.0f

#define BM 128
#define BN 128
#define BK 32
#define GRID_N (BATCH / BN)
#define GRID_M (BATCH / BM)

typedef __bf16 bf16_t;
typedef __bf16 v8bf __attribute__((ext_vector_type(8)));
typedef float v4f __attribute__((ext_vector_type(4)));

// async global->LDS, 16B per lane; LDS dest is wave-uniform base + lane*16
__device__ __forceinline__ void async16(const void* g, void* l) {
  __builtin_amdgcn_global_load_lds(
      (const __attribute__((address_space(1))) void*)g,
      (__attribute__((address_space(3))) void*)l, 16, 0, 0);
}

// ---------------- kernel 1: per-sample prep ----------------
__global__ __launch_bounds__(256) void prep_kernel(
    const float* __restrict__ z, const int* __restrict__ ages,
    const float* __restrict__ proxies,
    bf16_t* __restrict__ zb, bf16_t* __restrict__ wb,
    float* __restrict__ sq, float* __restrict__ hd)
{
  int j = blockIdx.x;
  int t = threadIdx.x;
  int a = ages[j];
  if (a < 0) a = 0;
  if (a > NUM_AGES - 1) a = NUM_AGES - 1;
  const float* cc = proxies + (size_t)a * FEAT;
  const float* cn = proxies + (size_t)(a + 1 > NUM_AGES - 1 ? NUM_AGES - 1 : a + 1) * FEAT;
  const float* cp = proxies + (size_t)(a - 1 < 0 ? 0 : a - 1) * FEAT;
  const float* zr = z + (size_t)j * FEAT;

  float zf[2], dff[2], dbf[2];
  float s_ff = 0.f, s_bb = 0.f, s_zz = 0.f, s_zf = 0.f, s_zb = 0.f;
#pragma unroll
  for (int e = 0; e < 2; ++e) {
    int c = t + e * 256;
    float ccv = cc[c];
    dff[e] = cn[c] - ccv;
    dbf[e] = cp[c] - ccv;
    zf[e] = zr[c];
    s_ff += dff[e] * dff[e];
    s_bb += dbf[e] * dbf[e];
    s_zz += zf[e] * zf[e];
    s_zf += zf[e] * dff[e];
    s_zb += zf[e] * dbf[e];
  }
#pragma unroll
  for (int off = 32; off > 0; off >>= 1) {
    s_ff += __shfl_down(s_ff, off, 64);
    s_bb += __shfl_down(s_bb, off, 64);
    s_zz += __shfl_down(s_zz, off, 64);
    s_zf += __shfl_down(s_zf, off, 64);
    s_zb += __shfl_down(s_zb, off, 64);
  }
  __shared__ float red[4][5];
  int wv = t >> 6, lane = t & 63;
  if (lane == 0) {
    red[wv][0] = s_ff; red[wv][1] = s_bb; red[wv][2] = s_zz;
    red[wv][3] = s_zf; red[wv][4] = s_zb;
  }
  __syncthreads();
  float ff = red[0][0] + red[1][0] + red[2][0] + red[3][0];
  float bb = red[0][1] + red[1][1] + red[2][1] + red[3][1];
  float zz = red[0][2] + red[1][2] + red[2][2] + red[3][2];
  float zdf = red[0][3] + red[1][3] + red[2][3] + red[3][3];
  float zdb = red[0][4] + red[1][4] + red[2][4] + red[3][4];

  float rf = 1.0f / (sqrtf(ff) + EPSF);
  float rb = 1.0f / (sqrtf(bb) + EPSF);
#pragma unroll
  for (int e = 0; e < 2; ++e) {
    int c = t + e * 256;
    float wval = dbf[e] * rb - dff[e] * rf;
    wb[(size_t)j * FEAT + c] = (bf16_t)wval;
    zb[(size_t)j * FEAT + c] = (bf16_t)zf[e];
  }
  if (t == 0) {
    sq[j] = zz;
    hd[j] = rb * zdb - rf * zdf;
  }
}

// ---------------- kernel 2: fused pairwise tile ----------------
// LDS layout per tile: 128 rows x 32 bf16 cols, rows of 64 B split into 4
// granules of 16 B. Granule q of row r is stored at position p = q ^ ((r>>1)&3)
// (XOR swizzle). This makes fragment ds_read_b128 exactly 2-way (free, m136)
// instead of 8-way, while keeping global_load_lds's lane-contiguous dest.
__global__ __launch_bounds__(256) void pair_kernel(
    const bf16_t* __restrict__ zb, const bf16_t* __restrict__ wb,
    const float* __restrict__ sq, const float* __restrict__ hd,
    const int* __restrict__ ages, float* __restrict__ partial)
{
  __shared__ __attribute__((aligned(16))) char lds[3 * BM * BK * 2]; // A | Z | W
  __shared__ float s_sqi[BM];
  __shared__ int   s_agei[BM];
  __shared__ float s_sqj[BN];
  __shared__ float s_hdj[BN];
  __shared__ int   s_agej[BN];
  __shared__ float wsum[4];

  int t = threadIdx.x;
  int wv = t >> 6, lane = t & 63;
  int i0 = blockIdx.y * BM, j0 = blockIdx.x * BN;

  if (t < BM) {
    s_sqi[t] = sq[i0 + t];
    s_agei[t] = ages[i0 + t];
  } else {
    int u = t - BM;
    s_sqj[u] = sq[j0 + u];
    s_hdj[u] = hd[j0 + u];
    s_agej[u] = ages[j0 + u];
  }

  v4f accG[4][4], accH[4][4];
#pragma unroll
  for (int a = 0; a < 4; ++a)
#pragma unroll
    for (int b = 0; b < 4; ++b) {
      accG[a][b] = (v4f){0.f, 0.f, 0.f, 0.f};
      accH[a][b] = (v4f){0.f, 0.f, 0.f, 0.f};
    }

  int wm = wv >> 1, wn = wv & 1;
  int lm = lane & 15, q = lane >> 4;
  int psw = (q ^ ((lm >> 1) & 3)) * 16;   // swizzled 16B-granule byte offset for fragment reads

  const bf16_t* gA = zb + (size_t)i0 * FEAT;
  const bf16_t* gZ = zb + (size_t)j0 * FEAT;
  const bf16_t* gW = wb + (size_t)j0 * FEAT;

  int grow = lane >> 2;                                // row within 16-row chunk
  int gq = (lane & 3) ^ ((lane >> 3) & 3);             // swizzle: global granule this lane fetches
  int gcol = gq * 8;                                   // bf16 element offset within K slab

  for (int k0 = 0; k0 < FEAT; k0 += BK) {
#pragma unroll
    for (int c2 = 0; c2 < 2; ++c2) {
      int chunk = wv * 2 + c2;                         // 0..7 : 16 rows each
      int row = chunk * 16 + grow;
      size_t goff = (size_t)row * FEAT + (size_t)(k0 + gcol);
      char* ldst = lds + chunk * 1024;                 // wave-uniform base
      async16(gA + goff, ldst);
      async16(gZ + goff, ldst + 8192);
      async16(gW + goff, ldst + 16384);
    }
    __syncthreads();

    v8bf afr[4], bz[4], bw[4];
#pragma unroll
    for (int mi = 0; mi < 4; ++mi) {
      int r = wm * 64 + mi * 16 + lm;
      afr[mi] = *(const v8bf*)(lds + r * 64 + psw);
    }
#pragma unroll
    for (int ni = 0; ni < 4; ++ni) {
      int r = wn * 64 + ni * 16 + lm;
      bz[ni] = *(const v8bf*)(lds + 8192 + r * 64 + psw);
      bw[ni] = *(const v8bf*)(lds + 16384 + r * 64 + psw);
    }
#pragma unroll
    for (int mi = 0; mi < 4; ++mi)
#pragma unroll
      for (int ni = 0; ni < 4; ++ni) {
        accG[mi][ni] = __builtin_amdgcn_mfma_f32_16x16x32_bf16(afr[mi], bz[ni], accG[mi][ni], 0, 0, 0);
        accH[mi][ni] = __builtin_amdgcn_mfma_f32_16x16x32_bf16(afr[mi], bw[ni], accH[mi][ni], 0, 0, 0);
      }
    __syncthreads();
  }

  // epilogue: C/D layout col = lane&15 (-> j), row = q*4 + reg (-> i)
  float sqi_l[16];
  int agei_l[16];
#pragma unroll
  for (int mi = 0; mi < 4; ++mi)
#pragma unroll
    for (int r = 0; r < 4; ++r) {
      int il = wm * 64 + mi * 16 + q * 4 + r;
      sqi_l[mi * 4 + r] = s_sqi[il];
      agei_l[mi * 4 + r] = s_agei[il];
    }

  float tsum = 0.f;
#pragma unroll
  for (int ni = 0; ni < 4; ++ni) {
    int jl = wn * 64 + ni * 16 + lm;
    float sqj = s_sqj[jl];
    float hdj = s_hdj[jl];
    int aj = s_agej[jl];
#pragma unroll
    for (int mi = 0; mi < 4; ++mi) {
#pragma unroll
      for (int r = 0; r < 4; ++r) {
        float g = accG[mi][ni][r];
        float h = accH[mi][ni][r];
        float sqi = sqi_l[mi * 4 + r];
        int ai = agei_l[mi * 4 + r];
        float d2 = fmaxf(sqi + sqj - 2.0f * g, 0.0f);
        float denom = sqrtf(d2) + EPSF;
        float arg = (h - hdj) * INV_T / denom;
        float x = fabsf(arg);
        float sp = fmaxf(arg, 0.0f) + __logf(1.0f + __expf(-x));
        tsum += (ai < aj) ? sp : 0.0f;
      }
    }
  }

#pragma unroll
  for (int off = 32; off > 0; off >>= 1) tsum += __shfl_down(tsum, off, 64);
  if (lane == 0) wsum[wv] = tsum;
  __syncthreads();
  if (t == 0)
    partial[blockIdx.y * gridDim.x + blockIdx.x] = wsum[0] + wsum[1] + wsum[2] + wsum[3];
}

// ---------------- kernel 3: final reduce ----------------
__global__ __launch_bounds__(256) void reduce_kernel(
    const float* __restrict__ partial, int n, float* __restrict__ out)
{
  int t = threadIdx.x;
  double s = 0.0;
  for (int idx = t; idx < n; idx += 256) s += (double)partial[idx];
#pragma unroll
  for (int off = 32; off > 0; off >>= 1) s += __shfl_down(s, off, 64);
  __shared__ double ws[4];
  int wv = t >> 6, lane = t & 63;
  if (lane == 0) ws[wv] = s;
  __syncthreads();
  if (t == 0) {
    double tot = ws[0] + ws[1] + ws[2] + ws[3];
    out[0] = (float)(tot / ((double)BATCH * (double)(BATCH - 1)));
  }
}

extern "C" void kernel_launch(void* const* d_in, const int* in_sizes, int n_in,
                              void* d_out, int out_size, void* d_ws, size_t ws_size,
                              hipStream_t stream) {
  const float* z = (const float*)d_in[0];
  const int* ages = (const int*)d_in[1];
  const float* proxies = (const float*)d_in[2];
  float* out = (float*)d_out;

  char* ws = (char*)d_ws;
  bf16_t* zb = (bf16_t*)ws;                                  // 4 MB
  bf16_t* wb = (bf16_t*)(ws + (size_t)4 * 1024 * 1024);      // 4 MB
  float* sq = (float*)(ws + (size_t)8 * 1024 * 1024);        // 16 KB
  float* hd = (float*)(ws + (size_t)8 * 1024 * 1024 + 16384);
  float* partial = (float*)(ws + (size_t)8 * 1024 * 1024 + 32768);

  prep_kernel<<<BATCH, 256, 0, stream>>>(z, ages, proxies, zb, wb, sq, hd);
  dim3 grid(GRID_N, GRID_M);
  pair_kernel<<<grid, 256, 0, stream>>>(zb, wb, sq, hd, ages, partial);
  reduce_kernel<<<1, 256, 0, stream>>>(partial, GRID_N * GRID_M, out);
}

// Round 3
// 118.954 us; speedup vs baseline: 1.3645x; 1.3406x over previous
//
#include <hip/hip_runtime.h>
#include <hip/hip_bf16.h>

#define NUM_AGES 100
#define FEAT 512
#define BATCH 4096
#define EPSF 1e-6f
#define INV_T 10.0f

#define BM 128
#define BN 64
#define BK 32
#define GRID_N (BATCH / BN)   // 64
#define GRID_M (BATCH / BM)   // 32

typedef __bf16 bf16_t;
typedef __bf16 v8bf __attribute__((ext_vector_type(8)));
typedef float v4f __attribute__((ext_vector_type(4)));

// async global->LDS, 16B per lane; LDS dest is wave-uniform base + lane*16
__device__ __forceinline__ void async16(const void* g, void* l) {
  __builtin_amdgcn_global_load_lds(
      (const __attribute__((address_space(1))) void*)g,
      (__attribute__((address_space(3))) void*)l, 16, 0, 0);
}

// ---------------- kernel 1: per-sample prep ----------------
__global__ __launch_bounds__(256) void prep_kernel(
    const float* __restrict__ z, const int* __restrict__ ages,
    const float* __restrict__ proxies,
    bf16_t* __restrict__ zb, bf16_t* __restrict__ wb,
    float* __restrict__ sq, float* __restrict__ hd)
{
  int j = blockIdx.x;
  int t = threadIdx.x;
  int a = ages[j];
  if (a < 0) a = 0;
  if (a > NUM_AGES - 1) a = NUM_AGES - 1;
  const float* cc = proxies + (size_t)a * FEAT;
  const float* cn = proxies + (size_t)(a + 1 > NUM_AGES - 1 ? NUM_AGES - 1 : a + 1) * FEAT;
  const float* cp = proxies + (size_t)(a - 1 < 0 ? 0 : a - 1) * FEAT;
  const float* zr = z + (size_t)j * FEAT;

  float zf[2], dff[2], dbf[2];
  float s_ff = 0.f, s_bb = 0.f, s_zz = 0.f, s_zf = 0.f, s_zb = 0.f;
#pragma unroll
  for (int e = 0; e < 2; ++e) {
    int c = t + e * 256;
    float ccv = cc[c];
    dff[e] = cn[c] - ccv;
    dbf[e] = cp[c] - ccv;
    zf[e] = zr[c];
    s_ff += dff[e] * dff[e];
    s_bb += dbf[e] * dbf[e];
    s_zz += zf[e] * zf[e];
    s_zf += zf[e] * dff[e];
    s_zb += zf[e] * dbf[e];
  }
#pragma unroll
  for (int off = 32; off > 0; off >>= 1) {
    s_ff += __shfl_down(s_ff, off, 64);
    s_bb += __shfl_down(s_bb, off, 64);
    s_zz += __shfl_down(s_zz, off, 64);
    s_zf += __shfl_down(s_zf, off, 64);
    s_zb += __shfl_down(s_zb, off, 64);
  }
  __shared__ float red[4][5];
  int wv = t >> 6, lane = t & 63;
  if (lane == 0) {
    red[wv][0] = s_ff; red[wv][1] = s_bb; red[wv][2] = s_zz;
    red[wv][3] = s_zf; red[wv][4] = s_zb;
  }
  __syncthreads();
  float ff = red[0][0] + red[1][0] + red[2][0] + red[3][0];
  float bb = red[0][1] + red[1][1] + red[2][1] + red[3][1];
  float zz = red[0][2] + red[1][2] + red[2][2] + red[3][2];
  float zdf = red[0][3] + red[1][3] + red[2][3] + red[3][3];
  float zdb = red[0][4] + red[1][4] + red[2][4] + red[3][4];

  float rf = 1.0f / (sqrtf(ff) + EPSF);
  float rb = 1.0f / (sqrtf(bb) + EPSF);
#pragma unroll
  for (int e = 0; e < 2; ++e) {
    int c = t + e * 256;
    float wval = dbf[e] * rb - dff[e] * rf;
    wb[(size_t)j * FEAT + c] = (bf16_t)wval;
    zb[(size_t)j * FEAT + c] = (bf16_t)zf[e];
  }
  if (t == 0) {
    sq[j] = zz;
    hd[j] = rb * zdb - rf * zdf;
  }
}

// ---------------- kernel 2: fused pairwise tile ----------------
// BM=128 x BN=64, acc = 64 AGPR/wave (G+H), arch-VGPR capped via
// __launch_bounds__(256,3) -> 3 waves/SIMD (R2 post-mortem: 128-AGPR acc
// pushed unified file to ~296 regs -> 1 wave/SIMD -> zero latency hiding).
__global__ __launch_bounds__(256, 3) void pair_kernel(
    const bf16_t* __restrict__ zb, const bf16_t* __restrict__ wb,
    const float* __restrict__ sq, const float* __restrict__ hd,
    const int* __restrict__ ages, float* __restrict__ partial)
{
  // A: 128x32 bf16 = 8192 B | Z: 64x32 = 4096 B | W: 64x32 = 4096 B
  __shared__ __attribute__((aligned(16))) char lds[16384];
  __shared__ float s_sqi[BM];
  __shared__ int   s_agei[BM];
  __shared__ float s_sqj[BN];
  __shared__ float s_hdj[BN];
  __shared__ int   s_agej[BN];
  __shared__ float wsum[4];

  int t = threadIdx.x;
  int wv = t >> 6, lane = t & 63;
  int i0 = blockIdx.y * BM, j0 = blockIdx.x * BN;

  if (t < BM) {
    s_sqi[t] = sq[i0 + t];
    s_agei[t] = ages[i0 + t];
  } else if (t < BM + BN) {
    int u = t - BM;
    s_sqj[u] = sq[j0 + u];
    s_hdj[u] = hd[j0 + u];
    s_agej[u] = ages[j0 + u];
  }

  v4f accG[4][2], accH[4][2];
#pragma unroll
  for (int a = 0; a < 4; ++a)
#pragma unroll
    for (int b = 0; b < 2; ++b) {
      accG[a][b] = (v4f){0.f, 0.f, 0.f, 0.f};
      accH[a][b] = (v4f){0.f, 0.f, 0.f, 0.f};
    }

  int wm = wv >> 1, wn = wv & 1;        // wave grid 2x2: 64 rows x 32 cols each
  int lm = lane & 15, q = lane >> 4;

  int grow = lane >> 2;                 // row within 16-row chunk
  int gcol = (lane & 3) * 8;            // bf16 element offset within 32-wide K slab

  // per-thread global pointers (monotonic, coalesced), advanced by BK per iter
  const bf16_t* pA0 = zb + (size_t)(i0 + wv * 16 + grow) * FEAT + gcol;        // chunks 0..3
  const bf16_t* pA1 = zb + (size_t)(i0 + 64 + wv * 16 + grow) * FEAT + gcol;   // chunks 4..7
  const bf16_t* pZ  = zb + (size_t)(j0 + wv * 16 + grow) * FEAT + gcol;
  const bf16_t* pW  = wb + (size_t)(j0 + wv * 16 + grow) * FEAT + gcol;
  char* dA0 = lds + wv * 1024;
  char* dA1 = lds + 4096 + wv * 1024;
  char* dZ  = lds + 8192 + wv * 1024;
  char* dW  = lds + 12288 + wv * 1024;

  for (int k0 = 0; k0 < FEAT; k0 += BK) {
    async16(pA0, dA0);
    async16(pA1, dA1);
    async16(pZ, dZ);
    async16(pW, dW);
    pA0 += BK; pA1 += BK; pZ += BK; pW += BK;
    __syncthreads();

    v8bf afr[4], bz[2], bw[2];
#pragma unroll
    for (int mi = 0; mi < 4; ++mi) {
      int r = wm * 64 + mi * 16 + lm;
      afr[mi] = *(const v8bf*)(lds + r * 64 + q * 16);
    }
#pragma unroll
    for (int ni = 0; ni < 2; ++ni) {
      int r = wn * 32 + ni * 16 + lm;
      bz[ni] = *(const v8bf*)(lds + 8192 + r * 64 + q * 16);
      bw[ni] = *(const v8bf*)(lds + 12288 + r * 64 + q * 16);
    }
#pragma unroll
    for (int mi = 0; mi < 4; ++mi)
#pragma unroll
      for (int ni = 0; ni < 2; ++ni) {
        accG[mi][ni] = __builtin_amdgcn_mfma_f32_16x16x32_bf16(afr[mi], bz[ni], accG[mi][ni], 0, 0, 0);
        accH[mi][ni] = __builtin_amdgcn_mfma_f32_16x16x32_bf16(afr[mi], bw[ni], accH[mi][ni], 0, 0, 0);
      }
    __syncthreads();
  }

  // epilogue: C/D layout col = lane&15 (-> j), row = q*4 + reg (-> i)
  float tsum = 0.f;
#pragma unroll
  for (int ni = 0; ni < 2; ++ni) {
    int jl = wn * 32 + ni * 16 + lm;
    float sqj = s_sqj[jl];
    float hdj = s_hdj[jl];
    int aj = s_agej[jl];
#pragma unroll
    for (int mi = 0; mi < 4; ++mi) {
#pragma unroll
      for (int r = 0; r < 4; ++r) {
        int il = wm * 64 + mi * 16 + q * 4 + r;
        float g = accG[mi][ni][r];
        float h = accH[mi][ni][r];
        float d2 = fmaxf(s_sqi[il] + sqj - 2.0f * g, 1e-12f);
        float rs = __builtin_amdgcn_rsqf(d2);      // v_rsq_f32: 1/(||zi-zj||), eps negligible
        float arg = (h - hdj) * INV_T * rs;
        float sp = fmaxf(arg, 0.0f) + __logf(1.0f + __expf(-fabsf(arg)));
        tsum += (s_agei[il] < aj) ? sp : 0.0f;
      }
    }
  }

#pragma unroll
  for (int off = 32; off > 0; off >>= 1) tsum += __shfl_down(tsum, off, 64);
  if (lane == 0) wsum[wv] = tsum;
  __syncthreads();
  if (t == 0)
    partial[blockIdx.y * gridDim.x + blockIdx.x] = wsum[0] + wsum[1] + wsum[2] + wsum[3];
}

// ---------------- kernel 3: final reduce ----------------
__global__ __launch_bounds__(256) void reduce_kernel(
    const float* __restrict__ partial, int n, float* __restrict__ out)
{
  int t = threadIdx.x;
  double s = 0.0;
  for (int idx = t; idx < n; idx += 256) s += (double)partial[idx];
#pragma unroll
  for (int off = 32; off > 0; off >>= 1) s += __shfl_down(s, off, 64);
  __shared__ double ws[4];
  int wv = t >> 6, lane = t & 63;
  if (lane == 0) ws[wv] = s;
  __syncthreads();
  if (t == 0) {
    double tot = ws[0] + ws[1] + ws[2] + ws[3];
    out[0] = (float)(tot / ((double)BATCH * (double)(BATCH - 1)));
  }
}

extern "C" void kernel_launch(void* const* d_in, const int* in_sizes, int n_in,
                              void* d_out, int out_size, void* d_ws, size_t ws_size,
                              hipStream_t stream) {
  const float* z = (const float*)d_in[0];
  const int* ages = (const int*)d_in[1];
  const float* proxies = (const float*)d_in[2];
  float* out = (float*)d_out;

  char* ws = (char*)d_ws;
  bf16_t* zb = (bf16_t*)ws;                                  // 4 MB
  bf16_t* wb = (bf16_t*)(ws + (size_t)4 * 1024 * 1024);      // 4 MB
  float* sq = (float*)(ws + (size_t)8 * 1024 * 1024);        // 16 KB
  float* hd = (float*)(ws + (size_t)8 * 1024 * 1024 + 16384);
  float* partial = (float*)(ws + (size_t)8 * 1024 * 1024 + 32768);

  prep_kernel<<<BATCH, 256, 0, stream>>>(z, ages, proxies, zb, wb, sq, hd);
  dim3 grid(GRID_N, GRID_M);
  pair_kernel<<<grid, 256, 0, stream>>>(zb, wb, sq, hd, ages, partial);
  reduce_kernel<<<1, 256, 0, stream>>>(partial, GRID_N * GRID_M, out);
}

// Round 4
// 108.690 us; speedup vs baseline: 1.4933x; 1.0944x over previous
//
#include <hip/hip_runtime.h>
#include <hip/hip_bf16.h>

#define NUM_AGES 100
#define FEAT 512
#define BATCH 4096
#define EPSF 1e-6f
#define INV_T 10.0f

#define BM 128
#define BN 64
#define BK 32
// kept tiles: bx >= 2*by, by in [0,32), bx in [0,64) -> sum(64-2*by) = 1056
#define NTILES 1056

typedef __bf16 bf16_t;
typedef __bf16 v8bf __attribute__((ext_vector_type(8)));
typedef float v4f __attribute__((ext_vector_type(4)));

// async global->LDS, 16B per lane; LDS dest is wave-uniform base + lane*16
__device__ __forceinline__ void async16(const void* g, void* l) {
  __builtin_amdgcn_global_load_lds(
      (const __attribute__((address_space(1))) void*)g,
      (__attribute__((address_space(3))) void*)l, 16, 0, 0);
}

// ---------------- kernel 0: counting sort by age ----------------
// perm[pos] = original index; pos ordered by nondecreasing age. Any
// permutation within an age bin is valid (loss is a sum over the
// age-defined pair set), so atomic rank assignment is fine.
__global__ __launch_bounds__(1024) void sort_kernel(
    const int* __restrict__ ages, int* __restrict__ perm)
{
  __shared__ int hist[NUM_AGES];
  __shared__ int base[NUM_AGES];
  int t = threadIdx.x;
  if (t < NUM_AGES) hist[t] = 0;
  __syncthreads();
  for (int j = t; j < BATCH; j += 1024) {
    int a = ages[j];
    a = a < 0 ? 0 : (a > NUM_AGES - 1 ? NUM_AGES - 1 : a);
    atomicAdd(&hist[a], 1);
  }
  __syncthreads();
  if (t == 0) {
    int s = 0;
    for (int a = 0; a < NUM_AGES; ++a) { base[a] = s; s += hist[a]; }
  }
  __syncthreads();
  for (int j = t; j < BATCH; j += 1024) {
    int a = ages[j];
    a = a < 0 ? 0 : (a > NUM_AGES - 1 ? NUM_AGES - 1 : a);
    int pos = atomicAdd(&base[a], 1);
    perm[pos] = j;
  }
}

// ---------------- kernel 1: per-sample prep (sorted order) ----------------
__global__ __launch_bounds__(256) void prep_kernel(
    const float* __restrict__ z, const int* __restrict__ ages,
    const float* __restrict__ proxies, const int* __restrict__ perm,
    bf16_t* __restrict__ zb, bf16_t* __restrict__ wb,
    float* __restrict__ sq, float* __restrict__ hd,
    int* __restrict__ ages_s)
{
  int j = blockIdx.x;          // sorted position
  int s = perm[j];             // original sample index
  int t = threadIdx.x;
  int araw = ages[s];
  int a = araw < 0 ? 0 : (araw > NUM_AGES - 1 ? NUM_AGES - 1 : araw);
  const float* cc = proxies + (size_t)a * FEAT;
  const float* cn = proxies + (size_t)(a + 1 > NUM_AGES - 1 ? NUM_AGES - 1 : a + 1) * FEAT;
  const float* cp = proxies + (size_t)(a - 1 < 0 ? 0 : a - 1) * FEAT;
  const float* zr = z + (size_t)s * FEAT;

  float zf[2], dff[2], dbf[2];
  float s_ff = 0.f, s_bb = 0.f, s_zz = 0.f, s_zf = 0.f, s_zb = 0.f;
#pragma unroll
  for (int e = 0; e < 2; ++e) {
    int c = t + e * 256;
    float ccv = cc[c];
    dff[e] = cn[c] - ccv;
    dbf[e] = cp[c] - ccv;
    zf[e] = zr[c];
    s_ff += dff[e] * dff[e];
    s_bb += dbf[e] * dbf[e];
    s_zz += zf[e] * zf[e];
    s_zf += zf[e] * dff[e];
    s_zb += zf[e] * dbf[e];
  }
#pragma unroll
  for (int off = 32; off > 0; off >>= 1) {
    s_ff += __shfl_down(s_ff, off, 64);
    s_bb += __shfl_down(s_bb, off, 64);
    s_zz += __shfl_down(s_zz, off, 64);
    s_zf += __shfl_down(s_zf, off, 64);
    s_zb += __shfl_down(s_zb, off, 64);
  }
  __shared__ float red[4][5];
  int wv = t >> 6, lane = t & 63;
  if (lane == 0) {
    red[wv][0] = s_ff; red[wv][1] = s_bb; red[wv][2] = s_zz;
    red[wv][3] = s_zf; red[wv][4] = s_zb;
  }
  __syncthreads();
  float ff = red[0][0] + red[1][0] + red[2][0] + red[3][0];
  float bb = red[0][1] + red[1][1] + red[2][1] + red[3][1];
  float zz = red[0][2] + red[1][2] + red[2][2] + red[3][2];
  float zdf = red[0][3] + red[1][3] + red[2][3] + red[3][3];
  float zdb = red[0][4] + red[1][4] + red[2][4] + red[3][4];

  float rf = 1.0f / (sqrtf(ff) + EPSF);
  float rb = 1.0f / (sqrtf(bb) + EPSF);
#pragma unroll
  for (int e = 0; e < 2; ++e) {
    int c = t + e * 256;
    float wval = dbf[e] * rb - dff[e] * rf;
    wb[(size_t)j * FEAT + c] = (bf16_t)wval;
    zb[(size_t)j * FEAT + c] = (bf16_t)zf[e];
  }
  if (t == 0) {
    sq[j] = zz;
    hd[j] = rb * zdb - rf * zdf;
    ages_s[j] = araw;
  }
}

// ---------------- kernel 2: fused pairwise tile (upper-tri band only) ----
// Samples are age-sorted; a tile with i_min >= j_max+1 has a_i >= a_j for
// every pair -> mask false -> contributes 0 -> skipped at grid level.
__global__ __launch_bounds__(256, 3) void pair_kernel(
    const bf16_t* __restrict__ zb, const bf16_t* __restrict__ wb,
    const float* __restrict__ sq, const float* __restrict__ hd,
    const int* __restrict__ ages, float* __restrict__ partial)
{
  // A: 128x32 bf16 = 8192 B | Z: 64x32 = 4096 B | W: 64x32 = 4096 B
  __shared__ __attribute__((aligned(16))) char lds[16384];
  __shared__ float s_sqi[BM];
  __shared__ int   s_agei[BM];
  __shared__ float s_sqj[BN];
  __shared__ float s_hdj[BN];
  __shared__ int   s_agej[BN];
  __shared__ float wsum[4];

  int t = threadIdx.x;
  int wv = t >> 6, lane = t & 63;

  // linear tile id -> (by, bx) with bx >= 2*by; row by has 64-2*by tiles
  int rem = blockIdx.x;
  int by = 0;
  while (rem >= 64 - 2 * by) { rem -= 64 - 2 * by; ++by; }
  int bx = 2 * by + rem;
  int i0 = by * BM, j0 = bx * BN;

  if (t < BM) {
    s_sqi[t] = sq[i0 + t];
    s_agei[t] = ages[i0 + t];
  } else if (t < BM + BN) {
    int u = t - BM;
    s_sqj[u] = sq[j0 + u];
    s_hdj[u] = hd[j0 + u];
    s_agej[u] = ages[j0 + u];
  }

  v4f accG[4][2], accH[4][2];
#pragma unroll
  for (int a = 0; a < 4; ++a)
#pragma unroll
    for (int b = 0; b < 2; ++b) {
      accG[a][b] = (v4f){0.f, 0.f, 0.f, 0.f};
      accH[a][b] = (v4f){0.f, 0.f, 0.f, 0.f};
    }

  int wm = wv >> 1, wn = wv & 1;        // wave grid 2x2: 64 rows x 32 cols each
  int lm = lane & 15, q = lane >> 4;

  int grow = lane >> 2;                 // row within 16-row chunk
  int gcol = (lane & 3) * 8;            // bf16 element offset within 32-wide K slab

  const bf16_t* pA0 = zb + (size_t)(i0 + wv * 16 + grow) * FEAT + gcol;
  const bf16_t* pA1 = zb + (size_t)(i0 + 64 + wv * 16 + grow) * FEAT + gcol;
  const bf16_t* pZ  = zb + (size_t)(j0 + wv * 16 + grow) * FEAT + gcol;
  const bf16_t* pW  = wb + (size_t)(j0 + wv * 16 + grow) * FEAT + gcol;
  char* dA0 = lds + wv * 1024;
  char* dA1 = lds + 4096 + wv * 1024;
  char* dZ  = lds + 8192 + wv * 1024;
  char* dW  = lds + 12288 + wv * 1024;

  for (int k0 = 0; k0 < FEAT; k0 += BK) {
    async16(pA0, dA0);
    async16(pA1, dA1);
    async16(pZ, dZ);
    async16(pW, dW);
    pA0 += BK; pA1 += BK; pZ += BK; pW += BK;
    __syncthreads();

    v8bf afr[4], bz[2], bw[2];
#pragma unroll
    for (int mi = 0; mi < 4; ++mi) {
      int r = wm * 64 + mi * 16 + lm;
      afr[mi] = *(const v8bf*)(lds + r * 64 + q * 16);
    }
#pragma unroll
    for (int ni = 0; ni < 2; ++ni) {
      int r = wn * 32 + ni * 16 + lm;
      bz[ni] = *(const v8bf*)(lds + 8192 + r * 64 + q * 16);
      bw[ni] = *(const v8bf*)(lds + 12288 + r * 64 + q * 16);
    }
#pragma unroll
    for (int mi = 0; mi < 4; ++mi)
#pragma unroll
      for (int ni = 0; ni < 2; ++ni) {
        accG[mi][ni] = __builtin_amdgcn_mfma_f32_16x16x32_bf16(afr[mi], bz[ni], accG[mi][ni], 0, 0, 0);
        accH[mi][ni] = __builtin_amdgcn_mfma_f32_16x16x32_bf16(afr[mi], bw[ni], accH[mi][ni], 0, 0, 0);
      }
    __syncthreads();
  }

  // epilogue: C/D layout col = lane&15 (-> j), row = q*4 + reg (-> i)
  float tsum = 0.f;
#pragma unroll
  for (int ni = 0; ni < 2; ++ni) {
    int jl = wn * 32 + ni * 16 + lm;
    float sqj = s_sqj[jl];
    float hdj = s_hdj[jl];
    int aj = s_agej[jl];
#pragma unroll
    for (int mi = 0; mi < 4; ++mi) {
#pragma unroll
      for (int r = 0; r < 4; ++r) {
        int il = wm * 64 + mi * 16 + q * 4 + r;
        float g = accG[mi][ni][r];
        float h = accH[mi][ni][r];
        float d2 = fmaxf(s_sqi[il] + sqj - 2.0f * g, 1e-12f);
        float rs = __builtin_amdgcn_rsqf(d2);
        float arg = (h - hdj) * INV_T * rs;
        float sp = fmaxf(arg, 0.0f) + __logf(1.0f + __expf(-fabsf(arg)));
        tsum += (s_agei[il] < aj) ? sp : 0.0f;
      }
    }
  }

#pragma unroll
  for (int off = 32; off > 0; off >>= 1) tsum += __shfl_down(tsum, off, 64);
  if (lane == 0) wsum[wv] = tsum;
  __syncthreads();
  if (t == 0)
    partial[blockIdx.x] = wsum[0] + wsum[1] + wsum[2] + wsum[3];
}

// ---------------- kernel 3: final reduce ----------------
__global__ __launch_bounds__(256) void reduce_kernel(
    const float* __restrict__ partial, int n, float* __restrict__ out)
{
  int t = threadIdx.x;
  double s = 0.0;
  for (int idx = t; idx < n; idx += 256) s += (double)partial[idx];
#pragma unroll
  for (int off = 32; off > 0; off >>= 1) s += __shfl_down(s, off, 64);
  __shared__ double ws[4];
  int wv = t >> 6, lane = t & 63;
  if (lane == 0) ws[wv] = s;
  __syncthreads();
  if (t == 0) {
    double tot = ws[0] + ws[1] + ws[2] + ws[3];
    out[0] = (float)(tot / ((double)BATCH * (double)(BATCH - 1)));
  }
}

extern "C" void kernel_launch(void* const* d_in, const int* in_sizes, int n_in,
                              void* d_out, int out_size, void* d_ws, size_t ws_size,
                              hipStream_t stream) {
  const float* z = (const float*)d_in[0];
  const int* ages = (const int*)d_in[1];
  const float* proxies = (const float*)d_in[2];
  float* out = (float*)d_out;

  char* ws = (char*)d_ws;
  bf16_t* zb = (bf16_t*)ws;                                   // 4 MB
  bf16_t* wb = (bf16_t*)(ws + (size_t)4 * 1024 * 1024);       // 4 MB
  size_t o = (size_t)8 * 1024 * 1024;
  float* sq      = (float*)(ws + o);            // 16 KB
  float* hd      = (float*)(ws + o + 16384);    // 16 KB
  float* partial = (float*)(ws + o + 32768);    // 16 KB (1056 used)
  int*   perm    = (int*)  (ws + o + 49152);    // 16 KB
  int*   ages_s  = (int*)  (ws + o + 65536);    // 16 KB

  sort_kernel<<<1, 1024, 0, stream>>>(ages, perm);
  prep_kernel<<<BATCH, 256, 0, stream>>>(z, ages, proxies, perm, zb, wb, sq, hd, ages_s);
  pair_kernel<<<NTILES, 256, 0, stream>>>(zb, wb, sq, hd, ages_s, partial);
  reduce_kernel<<<1, 256, 0, stream>>>(partial, NTILES, out);
}